// Round 2
// baseline (370.951 us; speedup 1.0000x reference)
//
#include <hip/hip_runtime.h>

#define NB 2048
#define NN 64
#define NC 256
#define EPSV 1e-5f

__device__ __forceinline__ float bits_to_f(unsigned u) {
    union { unsigned u; float f; } x; x.u = u; return x.f;
}
__device__ __forceinline__ unsigned f_to_bits(float f) {
    union { float f; unsigned u; } x; x.f = f; return x.u;
}
// round-to-nearest-even f32 -> bf16 bits
__device__ __forceinline__ unsigned short f2bf(float f) {
    unsigned u = f_to_bits(f);
    unsigned r = (u + 0x7fffu + ((u >> 16) & 1u)) >> 16;
    return (unsigned short)r;
}

extern "C" __global__ __launch_bounds__(256)
void dysep_fused(const float* __restrict__ q, const float* __restrict__ v,
                 const float* __restrict__ W, const float* __restrict__ bl,
                 const float* __restrict__ gam, const float* __restrict__ bet,
                 float* __restrict__ out)
{
    __shared__ __align__(16) float sDyw[64][68];            // 17408 B
    __shared__ __align__(16) unsigned short sDepth[64][260]; // 33280 B (bf16)

    const int tid = threadIdx.x;
    const int b = blockIdx.x;
    const long base = (long)b * (NN * NC);

    // ---------------- Phase 1: dyw = Q @ W^T + b_lin  (64x67) ----------------
    {
        const int tx = tid & 15, ty = tid >> 4;
        float acc[4][4];
        float accE[4];
#pragma unroll
        for (int r = 0; r < 4; ++r) {
            accE[r] = 0.f;
#pragma unroll
            for (int j = 0; j < 4; ++j) acc[r][j] = 0.f;
        }

        const float4* qr[4];
#pragma unroll
        for (int r = 0; r < 4; ++r)
            qr[r] = (const float4*)(q + base + (long)(ty * 4 + r) * NC);
        const float4* wr[4];
#pragma unroll
        for (int j = 0; j < 4; ++j)
            wr[j] = (const float4*)(W + (long)(tx + 16 * j) * NC);
        const int eo = (tx < 3) ? (64 + tx) : tx;  // extra col 64..66 (dummy=row tx)
        const float4* wrE = (const float4*)(W + (long)eo * NC);

#pragma unroll 2
        for (int cs = 0; cs < NC / 4; ++cs) {
            float4 qv[4], wv[4];
#pragma unroll
            for (int r = 0; r < 4; ++r) qv[r] = qr[r][cs];
#pragma unroll
            for (int j = 0; j < 4; ++j) wv[j] = wr[j][cs];
            float4 we = wrE[cs];
#pragma unroll
            for (int r = 0; r < 4; ++r) {
#pragma unroll
                for (int j = 0; j < 4; ++j) {
                    acc[r][j] += qv[r].x * wv[j].x + qv[r].y * wv[j].y
                               + qv[r].z * wv[j].z + qv[r].w * wv[j].w;
                }
                accE[r] += qv[r].x * we.x + qv[r].y * we.y
                         + qv[r].z * we.z + qv[r].w * we.w;
            }
        }
#pragma unroll
        for (int r = 0; r < 4; ++r) {
#pragma unroll
            for (int j = 0; j < 4; ++j)
                sDyw[ty * 4 + r][tx + 16 * j] = acc[r][j] + bl[tx + 16 * j];
        }
        if (tx < 3) {
#pragma unroll
            for (int r = 0; r < 4; ++r)
                sDyw[ty * 4 + r][64 + tx] = accE[r] + bl[64 + tx];
        }
    }
    __syncthreads();

    // ------- Phase 2: depth[n][c] = relu(conv3(value[n], dyw[n][0:3])) -> bf16 LDS -------
    {
        const int wid = tid >> 6, lane = tid & 63;
#pragma unroll 4
        for (int i = 0; i < 16; ++i) {
            const int n = i * 4 + wid;
            const float w0 = sDyw[n][0], w1 = sDyw[n][1], w2 = sDyw[n][2];
            float4 vv = *(const float4*)(v + base + (long)n * NC + 4 * lane);
            float prev = __shfl(vv.w, (lane + 63) & 63);
            float next = __shfl(vv.x, (lane + 1) & 63);
            if (lane == 0) prev = 0.f;
            if (lane == 63) next = 0.f;
            float d0 = fmaxf(0.f, w0 * prev + w1 * vv.x + w2 * vv.y);
            float d1 = fmaxf(0.f, w0 * vv.x + w1 * vv.y + w2 * vv.z);
            float d2 = fmaxf(0.f, w0 * vv.y + w1 * vv.z + w2 * vv.w);
            float d3 = fmaxf(0.f, w0 * vv.z + w1 * vv.w + w2 * next);
            ushort4 pk;
            pk.x = f2bf(d0); pk.y = f2bf(d1); pk.z = f2bf(d2); pk.w = f2bf(d3);
            *(ushort4*)&sDepth[n][4 * lane] = pk;
        }
    }
    __syncthreads();

    // ------- Phase 3: point = point_w @ depth, then LayerNorm, write out -------
    {
        const int wid = tid >> 6, lane = tid & 63;
        const float4 g4 = *(const float4*)(gam + 4 * lane);
        const float4 be4 = *(const float4*)(bet + 4 * lane);
#pragma unroll
        for (int pass = 0; pass < 4; ++pass) {
            const int m0 = wid * 16 + pass * 4;
            float4 acc[4];
#pragma unroll
            for (int r = 0; r < 4; ++r) acc[r] = make_float4(0.f, 0.f, 0.f, 0.f);

#pragma unroll 4
            for (int n = 0; n < 64; ++n) {
                uint2 rw = *(const uint2*)&sDepth[n][4 * lane];
                float f0 = bits_to_f(rw.x << 16);
                float f1 = bits_to_f(rw.x & 0xffff0000u);
                float f2 = bits_to_f(rw.y << 16);
                float f3 = bits_to_f(rw.y & 0xffff0000u);
                float p0 = sDyw[m0 + 0][n + 3];
                float p1 = sDyw[m0 + 1][n + 3];
                float p2 = sDyw[m0 + 2][n + 3];
                float p3 = sDyw[m0 + 3][n + 3];
                acc[0].x += p0 * f0; acc[0].y += p0 * f1; acc[0].z += p0 * f2; acc[0].w += p0 * f3;
                acc[1].x += p1 * f0; acc[1].y += p1 * f1; acc[1].z += p1 * f2; acc[1].w += p1 * f3;
                acc[2].x += p2 * f0; acc[2].y += p2 * f1; acc[2].z += p2 * f2; acc[2].w += p2 * f3;
                acc[3].x += p3 * f0; acc[3].y += p3 * f1; acc[3].z += p3 * f2; acc[3].w += p3 * f3;
            }
#pragma unroll
            for (int r = 0; r < 4; ++r) {
                float4 a = acc[r];
                float s1 = a.x + a.y + a.z + a.w;
                float s2 = a.x * a.x + a.y * a.y + a.z * a.z + a.w * a.w;
#pragma unroll
                for (int off = 1; off < 64; off <<= 1) {
                    s1 += __shfl_xor(s1, off);
                    s2 += __shfl_xor(s2, off);
                }
                float mu = s1 * (1.f / 256.f);
                float var = s2 * (1.f / 256.f) - mu * mu;
                float rs = rsqrtf(var + EPSV);
                float4 o;
                o.x = (a.x - mu) * rs * g4.x + be4.x;
                o.y = (a.y - mu) * rs * g4.y + be4.y;
                o.z = (a.z - mu) * rs * g4.z + be4.z;
                o.w = (a.w - mu) * rs * g4.w + be4.w;
                *(float4*)(out + base + (long)(m0 + r) * NC + 4 * lane) = o;
            }
        }
    }
}

extern "C" void kernel_launch(void* const* d_in, const int* in_sizes, int n_in,
                              void* d_out, int out_size, void* d_ws, size_t ws_size,
                              hipStream_t stream) {
    const float* q   = (const float*)d_in[0];
    const float* v   = (const float*)d_in[1];
    const float* W   = (const float*)d_in[2];
    const float* bl  = (const float*)d_in[3];
    const float* gam = (const float*)d_in[4];
    const float* bet = (const float*)d_in[5];
    float* o = (float*)d_out;
    hipLaunchKernelGGL(dysep_fused, dim3(NB), dim3(256), 0, stream,
                       q, v, W, bl, gam, bet, o);
}

// Round 4
// 125.300 us; speedup vs baseline: 2.9605x; 2.9605x over previous
//
#include <hip/hip_runtime.h>

#define NB 2048
#define NN 64
#define NC 256
#define EPSV 1e-5f

typedef __attribute__((ext_vector_type(8))) short bf16x8;
typedef __attribute__((ext_vector_type(4))) float f32x4;

union U8 { unsigned u[4]; unsigned long long d[2]; bf16x8 v; };

__device__ __forceinline__ unsigned f_bits(float f) {
    union { float f; unsigned u; } x; x.f = f; return x.u;
}
// round-half-up f32->bf16 (cheap, bias <= half ulp)
__device__ __forceinline__ unsigned short f2bf_r(float f) {
    return (unsigned short)((f_bits(f) + 0x8000u) >> 16);
}
// pack two f32 -> two bf16 in one u32 (lo = a, hi = b)
__device__ __forceinline__ unsigned pack2(float a, float b) {
    return ((f_bits(a) + 0x8000u) >> 16) | ((f_bits(b) + 0x8000u) & 0xffff0000u);
}

extern "C" __global__ __launch_bounds__(256, 3)
void dysep_mfma(const float* __restrict__ q, const float* __restrict__ v,
                const float* __restrict__ W, const float* __restrict__ bl,
                const float* __restrict__ gam, const float* __restrict__ bet,
                float* __restrict__ out)
{
    // LDS: 33792 + 8704 + 1024 = 43520 B -> 3 blocks/CU
    __shared__ __align__(16) unsigned short sDT[256 * 66];  // depth^T bf16 [c][n], pitch 66
    __shared__ __align__(16) unsigned short sPw[64][68];    // point_w bf16 [m][n], pitch 68
    __shared__ __align__(16) float sCw[64][4];              // conv weights f32

    const int tid = threadIdx.x;
    const int w  = tid >> 6;        // wave 0..3
    const int l  = tid & 63;
    const int lr = l & 15;          // 16-lane "row/col" index
    const int lg = l >> 4;          // 4-group index
    const long base = (long)blockIdx.x * (NN * NC);

    // ================= Phase 1: dyw = Q @ W^T + b  via MFMA =================
    // wave w owns M-tile w (rows w*16..+15); N-tiles nt=0..4 cover o=0..79 (o>=67 ignored)
    bf16x8 af[8];
    {
        const float* qrow = q + base + (long)(w * 16 + lr) * NC + lg * 8;
#pragma unroll
        for (int kg = 0; kg < 8; ++kg) {
            float4 a0 = *(const float4*)(qrow + kg * 32);
            float4 a1 = *(const float4*)(qrow + kg * 32 + 4);
            U8 u;
            u.u[0] = pack2(a0.x, a0.y); u.u[1] = pack2(a0.z, a0.w);
            u.u[2] = pack2(a1.x, a1.y); u.u[3] = pack2(a1.z, a1.w);
            af[kg] = u.v;
        }
    }
    f32x4 acc[5];
    {
        f32x4 zz = {0.f, 0.f, 0.f, 0.f};
#pragma unroll
        for (int nt = 0; nt < 5; ++nt) acc[nt] = zz;
    }
#pragma unroll
    for (int nt = 0; nt < 5; ++nt) {
        const int o = nt * 16 + lr;
        const int oc = (o < 67) ? o : 0;         // clamp to avoid OOB; result ignored
        const float* wrow = W + (long)oc * NC + lg * 8;
#pragma unroll
        for (int kg = 0; kg < 8; ++kg) {
            float4 b0 = *(const float4*)(wrow + kg * 32);
            float4 b1 = *(const float4*)(wrow + kg * 32 + 4);
            U8 u;
            u.u[0] = pack2(b0.x, b0.y); u.u[1] = pack2(b0.z, b0.w);
            u.u[2] = pack2(b1.x, b1.y); u.u[3] = pack2(b1.z, b1.w);
            acc[nt] = __builtin_amdgcn_mfma_f32_16x16x32_bf16(af[kg], u.v, acc[nt], 0, 0, 0);
        }
    }
    // epilogue: C/D layout col=lr (o within tile), row=lg*4+reg (m within tile)
#pragma unroll
    for (int nt = 0; nt < 5; ++nt) {
        const int o = nt * 16 + lr;
        const float bb = (o < 67) ? bl[o] : 0.f;
#pragma unroll
        for (int r = 0; r < 4; ++r) {
            const int m = w * 16 + lg * 4 + r;
            const float val = acc[nt][r] + bb;
            if (o < 3) sCw[m][o] = val;
            else if (o < 67) sPw[m][o - 3] = f2bf_r(val);
        }
    }
    __syncthreads();

    // ====== Phase 2: depth^T[c][n] = relu(conv3(V[n], cw[n])) (bf16) ======
    {
#pragma unroll 4
        for (int i = 0; i < 16; ++i) {
            const int n = i * 4 + w;
            const float w0 = sCw[n][0], w1 = sCw[n][1], w2 = sCw[n][2];
            float4 vv = *(const float4*)(v + base + (long)n * NC + 4 * l);
            float prev = __shfl(vv.w, (l + 63) & 63);
            float next = __shfl(vv.x, (l + 1) & 63);
            if (l == 0) prev = 0.f;
            if (l == 63) next = 0.f;
            const float d0 = fmaxf(0.f, w0 * prev + w1 * vv.x + w2 * vv.y);
            const float d1 = fmaxf(0.f, w0 * vv.x + w1 * vv.y + w2 * vv.z);
            const float d2 = fmaxf(0.f, w0 * vv.y + w1 * vv.z + w2 * vv.w);
            const float d3 = fmaxf(0.f, w0 * vv.z + w1 * vv.w + w2 * next);
            const int c0 = 4 * l;
            sDT[(c0 + 0) * 66 + n] = f2bf_r(d0);
            sDT[(c0 + 1) * 66 + n] = f2bf_r(d1);
            sDT[(c0 + 2) * 66 + n] = f2bf_r(d2);
            sDT[(c0 + 3) * 66 + n] = f2bf_r(d3);
        }
    }
    __syncthreads();

    // ======== Phase 3: point = pw @ depth via MFMA, then LayerNorm ========
    // wave w owns M-tile w; 16 c-tiles; K=64 -> 2 k-tiles
    bf16x8 pa[2];
#pragma unroll
    for (int kg = 0; kg < 2; ++kg) {
        const unsigned long long* p =
            (const unsigned long long*)&sPw[w * 16 + lr][kg * 32 + lg * 8];
        U8 u; u.d[0] = p[0]; u.d[1] = p[1];
        pa[kg] = u.v;
    }
    f32x4 acc3[16];
    {
        f32x4 zz = {0.f, 0.f, 0.f, 0.f};
#pragma unroll
        for (int ct = 0; ct < 16; ++ct) acc3[ct] = zz;
    }
#pragma unroll
    for (int ct = 0; ct < 16; ++ct) {
#pragma unroll
        for (int kg = 0; kg < 2; ++kg) {
            const unsigned* p = (const unsigned*)&sDT[(ct * 16 + lr) * 66 + kg * 32 + lg * 8];
            U8 u; u.u[0] = p[0]; u.u[1] = p[1]; u.u[2] = p[2]; u.u[3] = p[3];
            acc3[ct] = __builtin_amdgcn_mfma_f32_16x16x32_bf16(pa[kg], u.v, acc3[ct], 0, 0, 0);
        }
    }
    // LayerNorm: row m = w*16 + lg*4 + r; its 256 c-values live in the 16 lanes
    // of group lg (lr = c%16) x 16 c-tiles. Butterfly over lr (xor 1,2,4,8).
    float mus[4], rss[4];
#pragma unroll
    for (int r = 0; r < 4; ++r) {
        float s1 = 0.f, s2 = 0.f;
#pragma unroll
        for (int ct = 0; ct < 16; ++ct) {
            const float x = acc3[ct][r];
            s1 += x; s2 += x * x;
        }
#pragma unroll
        for (int off = 1; off < 16; off <<= 1) {
            s1 += __shfl_xor(s1, off);
            s2 += __shfl_xor(s2, off);
        }
        const float mu = s1 * (1.f / 256.f);
        const float var = s2 * (1.f / 256.f) - mu * mu;
        mus[r] = mu;
        rss[r] = rsqrtf(var + EPSV);
    }
    {
        float* orow = out + base + (long)(w * 16 + lg * 4) * NC + lr;
#pragma unroll
        for (int ct = 0; ct < 16; ++ct) {
            const float gg = gam[ct * 16 + lr];
            const float bb = bet[ct * 16 + lr];
#pragma unroll
            for (int r = 0; r < 4; ++r) {
                orow[(long)r * NC + ct * 16] =
                    (acc3[ct][r] - mus[r]) * rss[r] * gg + bb;
            }
        }
    }
}

extern "C" void kernel_launch(void* const* d_in, const int* in_sizes, int n_in,
                              void* d_out, int out_size, void* d_ws, size_t ws_size,
                              hipStream_t stream) {
    const float* q   = (const float*)d_in[0];
    const float* v   = (const float*)d_in[1];
    const float* W   = (const float*)d_in[2];
    const float* bl  = (const float*)d_in[3];
    const float* gam = (const float*)d_in[4];
    const float* bet = (const float*)d_in[5];
    float* o = (float*)d_out;
    hipLaunchKernelGGL(dysep_mfma, dim3(NB), dim3(256), 0, stream,
                       q, v, W, bl, gam, bet, o);
}

// Round 5
// 109.349 us; speedup vs baseline: 3.3924x; 1.1459x over previous
//
#include <hip/hip_runtime.h>

#define NB 2048
#define NN 64
#define NC 256
#define EPSV 1e-5f

typedef __attribute__((ext_vector_type(8))) short bf16x8;
typedef __attribute__((ext_vector_type(4))) float f32x4;

union U8 { unsigned u[4]; unsigned long long d[2]; bf16x8 v; };

__device__ __forceinline__ unsigned f_bits(float f) {
    union { float f; unsigned u; } x; x.f = f; return x.u;
}
// round-half-up f32->bf16
__device__ __forceinline__ unsigned short f2bf_r(float f) {
    return (unsigned short)((f_bits(f) + 0x8000u) >> 16);
}
// pack two f32 -> two bf16 in one u32 (lo = a, hi = b)
__device__ __forceinline__ unsigned pack2(float a, float b) {
    return ((f_bits(a) + 0x8000u) >> 16) | ((f_bits(b) + 0x8000u) & 0xffff0000u);
}

// ---- prep: pack W (f32 [67][256]) into bf16 MFMA B-fragments ----
// frag f = nt*8+kg (nt 0..4, kg 0..7), lane l: 8 bf16 of row o=nt*16+(l&15),
// k = kg*32 + (l>>4)*8 + e.  o >= 67 -> zeros.
extern "C" __global__ void prep_wfrag(const float* __restrict__ W,
                                      unsigned short* __restrict__ wf)
{
    const int idx = blockIdx.x * 256 + threadIdx.x;  // 0..2559
    if (idx >= 40 * 64) return;
    const int f = idx >> 6, l = idx & 63;
    const int nt = f >> 3, kg = f & 7;
    const int o = nt * 16 + (l & 15);
    const int kb = kg * 32 + (l >> 4) * 8;
    float x[8];
#pragma unroll
    for (int e = 0; e < 8; ++e)
        x[e] = (o < 67) ? W[o * NC + kb + e] : 0.f;
    uint4 pk;
    pk.x = pack2(x[0], x[1]); pk.y = pack2(x[2], x[3]);
    pk.z = pack2(x[4], x[5]); pk.w = pack2(x[6], x[7]);
    *(uint4*)(wf + (size_t)idx * 8) = pk;
}

extern "C" __global__ __launch_bounds__(512, 6)
void dysep_mfma8(const float* __restrict__ q, const float* __restrict__ v,
                 const unsigned short* __restrict__ wfrag,
                 const float* __restrict__ bl,
                 const float* __restrict__ gam, const float* __restrict__ bet,
                 float* __restrict__ out)
{
    // LDS: 33792 + 8704 + 1024 + 1024 = 44544 B -> 3 blocks/CU (24 waves)
    __shared__ __align__(16) unsigned short sDT[256 * 66];  // depth^T bf16 [c][n], pitch 66
    __shared__ __align__(16) unsigned short sPw[64][68];    // point_w bf16 [m][n], pitch 68
    __shared__ __align__(16) float sCw[64][4];              // conv weights f32
    __shared__ __align__(16) float sLN[64][4];              // per-row {s1_h0,s2_h0,s1_h1,s2_h1}

    const int tid = threadIdx.x;
    const int w  = tid >> 6;        // wave 0..7
    const int mt = w & 3;           // m-tile 0..3
    const int h  = w >> 2;          // half 0/1
    const int l  = tid & 63;
    const int lr = l & 15;
    const int lg = l >> 4;
    const long base = (long)blockIdx.x * (NN * NC);

    // ================= Phase 1: dyw = Q @ W^T + b  via MFMA =================
    // wave (mt,h): rows mt*16..+15, nt = h*3 + t, t < (3-h)
    bf16x8 af[8];
    {
        const float* qrow = q + base + (long)(mt * 16 + lr) * NC + lg * 8;
#pragma unroll
        for (int kg = 0; kg < 8; ++kg) {
            float4 a0 = *(const float4*)(qrow + kg * 32);
            float4 a1 = *(const float4*)(qrow + kg * 32 + 4);
            U8 u;
            u.u[0] = pack2(a0.x, a0.y); u.u[1] = pack2(a0.z, a0.w);
            u.u[2] = pack2(a1.x, a1.y); u.u[3] = pack2(a1.z, a1.w);
            af[kg] = u.v;
        }
    }
    const int ntCount = 3 - h;
    f32x4 acc[3];
    {
        f32x4 zz = {0.f, 0.f, 0.f, 0.f};
#pragma unroll
        for (int t = 0; t < 3; ++t) acc[t] = zz;
    }
    const U8* __restrict__ wf8 = (const U8*)wfrag;
#pragma unroll
    for (int t = 0; t < 3; ++t) {
        if (t < ntCount) {
            const int nt = h * 3 + t;
            const U8* fr = wf8 + (nt * 8) * 64 + l;
#pragma unroll
            for (int kg = 0; kg < 8; ++kg) {
                U8 u = fr[kg * 64];
                acc[t] = __builtin_amdgcn_mfma_f32_16x16x32_bf16(af[kg], u.v, acc[t], 0, 0, 0);
            }
        }
    }
    // epilogue: C/D layout col=lr (o within tile), row=lg*4+r (m within tile)
#pragma unroll
    for (int t = 0; t < 3; ++t) {
        if (t < ntCount) {
            const int o = (h * 3 + t) * 16 + lr;
            const float bb = (o < 67) ? bl[o] : 0.f;
#pragma unroll
            for (int r = 0; r < 4; ++r) {
                const int m = mt * 16 + lg * 4 + r;
                const float val = acc[t][r] + bb;
                if (o < 3) sCw[m][o] = val;
                else if (o < 67) sPw[m][o - 3] = f2bf_r(val);
            }
        }
    }
    __syncthreads();

    // ====== Phase 2: depth^T[c][n] = relu(conv3(V[n], cw[n])) (bf16) ======
    {
#pragma unroll 4
        for (int i = 0; i < 8; ++i) {
            const int n = i * 8 + w;
            const float w0 = sCw[n][0], w1 = sCw[n][1], w2 = sCw[n][2];
            float4 vv = *(const float4*)(v + base + (long)n * NC + 4 * l);
            float prev = __shfl(vv.w, (l + 63) & 63);
            float next = __shfl(vv.x, (l + 1) & 63);
            if (l == 0) prev = 0.f;
            if (l == 63) next = 0.f;
            const float d0 = fmaxf(0.f, w0 * prev + w1 * vv.x + w2 * vv.y);
            const float d1 = fmaxf(0.f, w0 * vv.x + w1 * vv.y + w2 * vv.z);
            const float d2 = fmaxf(0.f, w0 * vv.y + w1 * vv.z + w2 * vv.w);
            const float d3 = fmaxf(0.f, w0 * vv.z + w1 * vv.w + w2 * next);
            const int c0 = 4 * l;
            sDT[(c0 + 0) * 66 + n] = f2bf_r(d0);
            sDT[(c0 + 1) * 66 + n] = f2bf_r(d1);
            sDT[(c0 + 2) * 66 + n] = f2bf_r(d2);
            sDT[(c0 + 3) * 66 + n] = f2bf_r(d3);
        }
    }
    __syncthreads();

    // ======== Phase 3: point = pw @ depth via MFMA (wave: mt x c-half h) ========
    bf16x8 pa[2];
#pragma unroll
    for (int kg = 0; kg < 2; ++kg) {
        const unsigned long long* p =
            (const unsigned long long*)&sPw[mt * 16 + lr][kg * 32 + lg * 8];
        U8 u; u.d[0] = p[0]; u.d[1] = p[1];
        pa[kg] = u.v;
    }
    f32x4 acc3[8];
    {
        f32x4 zz = {0.f, 0.f, 0.f, 0.f};
#pragma unroll
        for (int t = 0; t < 8; ++t) acc3[t] = zz;
    }
#pragma unroll
    for (int t = 0; t < 8; ++t) {
        const int ct = h * 8 + t;
#pragma unroll
        for (int kg = 0; kg < 2; ++kg) {
            const unsigned* p = (const unsigned*)&sDT[(ct * 16 + lr) * 66 + kg * 32 + lg * 8];
            U8 u; u.u[0] = p[0]; u.u[1] = p[1]; u.u[2] = p[2]; u.u[3] = p[3];
            acc3[t] = __builtin_amdgcn_mfma_f32_16x16x32_bf16(pa[kg], u.v, acc3[t], 0, 0, 0);
        }
    }
    // partial LN sums over this wave's 8 c-tiles; butterfly over lr (within 16)
    {
        float s1a[4], s2a[4];
#pragma unroll
        for (int r = 0; r < 4; ++r) {
            float s1 = 0.f, s2 = 0.f;
#pragma unroll
            for (int t = 0; t < 8; ++t) {
                const float x = acc3[t][r];
                s1 += x; s2 += x * x;
            }
#pragma unroll
            for (int off = 1; off < 16; off <<= 1) {
                s1 += __shfl_xor(s1, off);
                s2 += __shfl_xor(s2, off);
            }
            s1a[r] = s1; s2a[r] = s2;
        }
        if (lr == 0) {
#pragma unroll
            for (int r = 0; r < 4; ++r) {
                const int m = mt * 16 + lg * 4 + r;
                sLN[m][2 * h + 0] = s1a[r];
                sLN[m][2 * h + 1] = s2a[r];
            }
        }
    }
    __syncthreads();

    float mus[4], rss[4];
#pragma unroll
    for (int r = 0; r < 4; ++r) {
        const int m = mt * 16 + lg * 4 + r;
        const float S1 = sLN[m][0] + sLN[m][2];
        const float S2 = sLN[m][1] + sLN[m][3];
        const float mu = S1 * (1.f / 256.f);
        const float var = S2 * (1.f / 256.f) - mu * mu;
        mus[r] = mu;
        rss[r] = rsqrtf(var + EPSV);
    }
    {
        float* orow = out + base + (long)(mt * 16 + lg * 4) * NC + lr;
#pragma unroll
        for (int t = 0; t < 8; ++t) {
            const int ct = h * 8 + t;
            const float gg = gam[ct * 16 + lr];
            const float bb = bet[ct * 16 + lr];
#pragma unroll
            for (int r = 0; r < 4; ++r) {
                orow[(long)r * NC + ct * 16] =
                    (acc3[t][r] - mus[r]) * rss[r] * gg + bb;
            }
        }
    }
}

extern "C" void kernel_launch(void* const* d_in, const int* in_sizes, int n_in,
                              void* d_out, int out_size, void* d_ws, size_t ws_size,
                              hipStream_t stream) {
    const float* q   = (const float*)d_in[0];
    const float* v   = (const float*)d_in[1];
    const float* W   = (const float*)d_in[2];
    const float* bl  = (const float*)d_in[3];
    const float* gam = (const float*)d_in[4];
    const float* bet = (const float*)d_in[5];
    float* o = (float*)d_out;
    unsigned short* wf = (unsigned short*)d_ws;   // 40*64*16 B = 40960 B

    hipLaunchKernelGGL(prep_wfrag, dim3(10), dim3(256), 0, stream, W, wf);
    hipLaunchKernelGGL(dysep_mfma8, dim3(NB), dim3(512), 0, stream,
                       q, v, wf, bl, gam, bet, o);
}